// Round 8
// baseline (187.627 us; speedup 1.0000x reference)
//
#include <hip/hip_runtime.h>
#include <hip/hip_bf16.h>

#define D_MODEL 1280
#define NUM_HEADS 16
#define D_K 80
#define DP 96            // head dim padded to 3*32 for MFMA K-steps
#define SEQ 1024
#define BATCH 4
#define BH (BATCH*NUM_HEADS)

typedef __hip_bfloat16 bf16;
typedef short short8 __attribute__((ext_vector_type(8)));
typedef short short4v __attribute__((ext_vector_type(4)));
typedef float f32x4 __attribute__((ext_vector_type(4)));

__device__ __forceinline__ float b2f(bf16 x) { return __bfloat162float(x); }
__device__ __forceinline__ bf16 f2b(float x) { return __float2bfloat16(x); }
__device__ __forceinline__ short bbits(float x) {
    union { bf16 b; short s; } u; u.b = __float2bfloat16(x); return u.s;
}

#define MFMA16(a, b, c) __builtin_amdgcn_mfma_f32_16x16x32_bf16(a, b, c, 0, 0, 0)

// ---------------------------------------------------------------------------
// Kernel 0 (merged): pack Wq|Wk|Wv -> Wcat[h][240][96] bf16 with the
// channel-shuffle permutation folded into the K(input)-dim. Also Wo -> bf16.
// ---------------------------------------------------------------------------
__global__ __launch_bounds__(256) void cvt_all_kernel(
    const float* __restrict__ Wq, const float* __restrict__ Wk,
    const float* __restrict__ Wv, bf16* __restrict__ Wcat,
    const float* __restrict__ Wo, bf16* __restrict__ Wb)
{
    if (blockIdx.x < 1440) {
        int idx = blockIdx.x * 256 + threadIdx.x;
        int col = idx % 96;
        int row = (idx / 96) % 240;
        int h   = idx / (96 * 240);
        int mat = row / 80, e = row % 80;
        int c = col >> 4, j = col & 15;          // e' = c*16 + j
        const float* W = (mat == 0) ? Wq : (mat == 1) ? Wk : Wv;
        float v = (col < 80) ? W[(size_t)(h * 80 + e) * 80 + (j * 5 + c)] : 0.f;
        Wcat[idx] = f2b(v);
    } else {
        int idx = ((blockIdx.x - 1440) * 256 + threadIdx.x) * 4;
        float4 v = *(const float4*)(Wo + idx);
        Wb[idx]     = f2b(v.x);
        Wb[idx + 1] = f2b(v.y);
        Wb[idx + 2] = f2b(v.z);
        Wb[idx + 3] = f2b(v.w);
    }
}

// ---------------------------------------------------------------------------
// Kernel 1: per-head QKV projection via MFMA, register-direct X fragments.
// V is stored in PV-FRAGMENT order so attn reads it with fully-coalesced
// per-wave 1KB loads: Vg[bh][kt][js][ne][lcol=e&15][lquad_s][jj] where the
// token slot (js,lquad_s,jj) encodes perm6: token = js*32 + (jj>>2)*16 +
// lquad_s*4 + (jj&3). Numerically identical to r7's perm6 Vt layout.
// ---------------------------------------------------------------------------
__global__ __launch_bounds__(256) void qkv_kernel(
    const float* __restrict__ src,
    const float* __restrict__ bq, const float* __restrict__ bk,
    const float* __restrict__ bv, const bf16* __restrict__ Wcat,
    bf16* __restrict__ Qb, bf16* __restrict__ Kb, bf16* __restrict__ Vg)
{
    const int h = blockIdx.y;
    const int b = blockIdx.x >> 3;
    const int s0 = (blockIdx.x & 7) * 128;
    const int tid = threadIdx.x;
    const int wave = tid >> 6, lane = tid & 63;
    const int lquad = lane >> 4, lcol = lane & 15;
    const int bh = b * NUM_HEADS + h;

    // X fragments straight from global (permuted-K ordering)
    short8 xf[2][3];
    #pragma unroll
    for (int mt = 0; mt < 2; mt++)
        #pragma unroll
        for (int ks = 0; ks < 3; ks++) {
            const int c  = 2 * ks + (lquad >> 1);
            const int j0 = (lquad & 1) * 8;
            short8 t = {0, 0, 0, 0, 0, 0, 0, 0};
            if (c < 5) {   // c==5 is the zero pad (W pad cols are zero too)
                const float* p = src
                    + (size_t)(b * SEQ + s0 + wave * 32 + mt * 16 + lcol) * D_MODEL
                    + c * 256 + h * 16 + j0;
                float4 v0 = *(const float4*)p;
                float4 v1 = *(const float4*)(p + 4);
                t[0] = bbits(v0.x); t[1] = bbits(v0.y);
                t[2] = bbits(v0.z); t[3] = bbits(v0.w);
                t[4] = bbits(v1.x); t[5] = bbits(v1.y);
                t[6] = bbits(v1.z); t[7] = bbits(v1.w);
            }
            xf[mt][ks] = t;
        }

    const bf16* Wh = Wcat + (size_t)h * 240 * 96;
    const float qscale = 1.4426950408889634f * 0.11180339887498949f;
    const f32x4 fzero = {0.f, 0.f, 0.f, 0.f};

    // ---- Q and K: D[token][e] ----
    #pragma unroll
    for (int mat = 0; mat < 2; mat++) {
        const bf16* Wm = Wh + mat * 80 * 96;
        short8 wf[5][3];
        #pragma unroll
        for (int n = 0; n < 5; n++)
            #pragma unroll
            for (int ks = 0; ks < 3; ks++)
                wf[n][ks] = *(const short8*)(Wm + (n*16 + lcol)*96 + ks*32 + lquad*8);

        f32x4 acc[2][5];
        #pragma unroll
        for (int n = 0; n < 5; n++) {          // first ks folds zero-init
            acc[0][n] = MFMA16(xf[0][0], wf[n][0], fzero);
            acc[1][n] = MFMA16(xf[1][0], wf[n][0], fzero);
        }
        #pragma unroll
        for (int ks = 1; ks < 3; ks++)
            #pragma unroll
            for (int n = 0; n < 5; n++) {
                acc[0][n] = MFMA16(xf[0][ks], wf[n][ks], acc[0][n]);
                acc[1][n] = MFMA16(xf[1][ks], wf[n][ks], acc[1][n]);
            }

        const float* bias = (mat == 0) ? bq : bk;
        bf16* Out = (mat == 0) ? Qb : Kb;
        const float scale = (mat == 0) ? qscale : 1.f;
        #pragma unroll
        for (int n = 0; n < 5; n++) {
            float bb = bias[h * 80 + n * 16 + lcol];
            #pragma unroll
            for (int mt = 0; mt < 2; mt++)
                #pragma unroll
                for (int r = 0; r < 4; r++) {
                    int srow = s0 + wave*32 + mt*16 + lquad*4 + r;
                    Out[((size_t)bh * SEQ + srow) * DP + n*16 + lcol] =
                        f2b((acc[mt][n][r] + bb) * scale);
                }
        }
    }
    // zero pad e = 80..95 for Q and K (128 rows, 256 threads)
    {
        int i = tid >> 1, half = tid & 1;
        size_t row = ((size_t)bh * SEQ + s0 + i) * DP + 80 + half * 8;
        *(uint4*)(Qb + row) = make_uint4(0, 0, 0, 0);
        *(uint4*)(Kb + row) = make_uint4(0, 0, 0, 0);
    }

    // ---- V: PV-fragment-order store ----
    {
        const bf16* Wm = Wh + 2 * 80 * 96;
        short8 wf[5][3];
        #pragma unroll
        for (int m = 0; m < 5; m++)
            #pragma unroll
            for (int ks = 0; ks < 3; ks++)
                wf[m][ks] = *(const short8*)(Wm + (m*16 + lcol)*96 + ks*32 + lquad*8);

        f32x4 acc[5][2];
        #pragma unroll
        for (int m = 0; m < 5; m++) {          // first ks folds zero-init
            acc[m][0] = MFMA16(wf[m][0], xf[0][0], fzero);
            acc[m][1] = MFMA16(wf[m][0], xf[1][0], fzero);
        }
        #pragma unroll
        for (int ks = 1; ks < 3; ks++)
            #pragma unroll
            for (int m = 0; m < 5; m++) {
                acc[m][0] = MFMA16(wf[m][ks], xf[0][ks], acc[m][0]);
                acc[m][1] = MFMA16(wf[m][ks], xf[1][ks], acc[m][1]);
            }

        #pragma unroll
        for (int m = 0; m < 5; m++) {
            float4 bb4 = *(const float4*)(bv + h * 80 + m * 16 + lquad * 4);
            float bb[4] = {bb4.x, bb4.y, bb4.z, bb4.w};
            #pragma unroll
            for (int nt = 0; nt < 2; nt++)
                #pragma unroll
                for (int r = 0; r < 4; r++) {
                    int elow  = lquad * 4 + r;           // e & 15
                    int token = s0 + wave * 32 + nt * 16 + lcol;
                    int kt  = token >> 6;
                    int js  = (token >> 5) & 1;
                    int jj  = ((token >> 4) & 1) * 4 + (token & 3);
                    int lqs = (token >> 2) & 3;
                    size_t el = (size_t)bh * 81920
                              + (size_t)((kt * 2 + js) * 5 + m) * 512
                              + elow * 32 + lqs * 8 + jj;
                    Vg[el] = f2b(acc[m][nt][r] + bb[r]);
                }
        }
    }
}

// ---------------------------------------------------------------------------
// Kernel 2: MFMA flash attention.
//  - P fully lane-local (r7), V read from L2 in PV-fragment order: one
//    COALESCED 1KB load per (js,ne) per wave, issued at iteration top (T14).
//    This fixes r5/r6's 16-segment-gather throughput problem.
//  - K double-buffered in LDS (Qs region freed by r7) -> ONE barrier/iter.
//  - Q fragments direct from global (once). LDS 26,624 B = Ks0|Ks1.
// ---------------------------------------------------------------------------
__global__ __launch_bounds__(128, 2) void attn_kernel(
    const bf16* __restrict__ Qb, const bf16* __restrict__ Kb,
    const bf16* __restrict__ Vg, bf16* __restrict__ Cc)
{
    __shared__ char smem[26624];
    bf16* Ks0 = (bf16*)smem;
    bf16* Ks1 = (bf16*)(smem + 13312);

    const int tid = threadIdx.x;
    const int wave = tid >> 6, lane = tid & 63;
    const int lquad = lane >> 4, lcol = lane & 15;
    const int bh = blockIdx.x;
    const int b = bh >> 4, h = bh & 15;
    const int q0 = blockIdx.y * 64;

    const uint4* Kg = (const uint4*)(Kb + (size_t)bh * SEQ * DP);
    // V: per-lane offset inside each coalesced 512-element fragment block
    const bf16* Vb = Vg + (size_t)bh * 81920 + lcol * 32 + lquad * 8;

    // K staging map as individual scalars (NO arrays -> no scratch demotion)
    const int i0 = tid, i1 = tid + 128, i2 = tid + 256,
              i3 = tid + 384, i4 = tid + 512, i5 = tid + 640;
    const int kd0 = (i0/12)*104 + (i0%12)*8, kd1 = (i1/12)*104 + (i1%12)*8,
              kd2 = (i2/12)*104 + (i2%12)*8, kd3 = (i3/12)*104 + (i3%12)*8,
              kd4 = (i4/12)*104 + (i4%12)*8, kd5 = (i5/12)*104 + (i5%12)*8;

    // Q fragments direct from global (read once per block)
    short8 qf[2][3];
    #pragma unroll
    for (int nt = 0; nt < 2; nt++)
        #pragma unroll
        for (int ks = 0; ks < 3; ks++)
            qf[nt][ks] = *(const short8*)(
                Qb + ((size_t)bh * SEQ + q0 + wave*32 + nt*16 + lcol) * DP
                   + ks*32 + lquad*8);

    // stage K tile 0 into Ks0
    *(uint4*)(Ks0 + kd0) = Kg[i0];
    *(uint4*)(Ks0 + kd1) = Kg[i1];
    *(uint4*)(Ks0 + kd2) = Kg[i2];
    *(uint4*)(Ks0 + kd3) = Kg[i3];
    *(uint4*)(Ks0 + kd4) = Kg[i4];
    *(uint4*)(Ks0 + kd5) = Kg[i5];
    __syncthreads();

    f32x4 Oacc[2][5];
    #pragma unroll
    for (int mt = 0; mt < 2; mt++)
        #pragma unroll
        for (int ne = 0; ne < 5; ne++)
            #pragma unroll
            for (int r = 0; r < 4; r++) Oacc[mt][ne][r] = 0.f;

    f32x4 lsum4[2];
    #pragma unroll
    for (int nt = 0; nt < 2; nt++)
        #pragma unroll
        for (int r = 0; r < 4; r++) lsum4[nt][r] = 0.f;

    const f32x4 fzero = {0.f, 0.f, 0.f, 0.f};

    for (int kt = 0; kt < 16; kt++) {
        const bf16* cur = (kt & 1) ? Ks1 : Ks0;
        bf16*       nxt = (kt & 1) ? Ks0 : Ks1;

        // V fragments for THIS tile: coalesced 1KB/wave loads, issued early
        const bf16* Vk = Vb + (size_t)kt * 5120;
        short8 v00 = *(const short8*)(Vk);              // js=0, ne=0
        short8 v01 = *(const short8*)(Vk + 512);
        short8 v02 = *(const short8*)(Vk + 1024);
        short8 v03 = *(const short8*)(Vk + 1536);
        short8 v04 = *(const short8*)(Vk + 2048);
        short8 v10 = *(const short8*)(Vk + 2560);       // js=1, ne=0
        short8 v11 = *(const short8*)(Vk + 3072);
        short8 v12 = *(const short8*)(Vk + 3584);
        short8 v13 = *(const short8*)(Vk + 4096);
        short8 v14 = *(const short8*)(Vk + 4608);

        // T14: next K tile into scalar regs; straight-line (wraps at end)
        const int ktn = (kt + 1) & 15;
        uint4 kA = Kg[ktn * 768 + i0];
        uint4 kB = Kg[ktn * 768 + i1];
        uint4 kC = Kg[ktn * 768 + i2];
        uint4 kD = Kg[ktn * 768 + i3];
        uint4 kE = Kg[ktn * 768 + i4];
        uint4 kF = Kg[ktn * 768 + i5];

        // S^T = K·Q^T (first ks folds the zero-init)
        f32x4 st[4][2];
        __builtin_amdgcn_s_setprio(1);
        #pragma unroll
        for (int mt = 0; mt < 4; mt++) {
            short8 af = *(const short8*)(cur + (mt*16 + lcol)*104 + lquad*8);
            st[mt][0] = MFMA16(af, qf[0][0], fzero);
            st[mt][1] = MFMA16(af, qf[1][0], fzero);
        }
        #pragma unroll
        for (int ks = 1; ks < 3; ks++)
            #pragma unroll
            for (int mt = 0; mt < 4; mt++) {
                short8 af = *(const short8*)(cur + (mt*16 + lcol)*104 + ks*32 + lquad*8);
                st[mt][0] = MFMA16(af, qf[0][ks], st[mt][0]);
                st[mt][1] = MFMA16(af, qf[1][ks], st[mt][1]);
            }
        __builtin_amdgcn_s_setprio(0);

        // softmax + PV, fused per js; P fragments lane-local (r7 layout)
        // js = 0: st[0], st[1]
        {
            short8 pf0, pf1;
            #pragma unroll
            for (int half = 0; half < 2; half++)
                #pragma unroll
                for (int r = 0; r < 4; r++) {
                    float p0 = __builtin_amdgcn_exp2f(st[half][0][r]);
                    float p1 = __builtin_amdgcn_exp2f(st[half][1][r]);
                    lsum4[0][r] += p0;
                    lsum4[1][r] += p1;
                    pf0[half*4+r] = bbits(p0);
                    pf1[half*4+r] = bbits(p1);
                }
            __builtin_amdgcn_s_setprio(1);
            Oacc[0][0] = MFMA16(pf0, v00, Oacc[0][0]);
            Oacc[1][0] = MFMA16(pf1, v00, Oacc[1][0]);
            Oacc[0][1] = MFMA16(pf0, v01, Oacc[0][1]);
            Oacc[1][1] = MFMA16(pf1, v01, Oacc[1][1]);
            Oacc[0][2] = MFMA16(pf0, v02, Oacc[0][2]);
            Oacc[1][2] = MFMA16(pf1, v02, Oacc[1][2]);
            Oacc[0][3] = MFMA16(pf0, v03, Oacc[0][3]);
            Oacc[1][3] = MFMA16(pf1, v03, Oacc[1][3]);
            Oacc[0][4] = MFMA16(pf0, v04, Oacc[0][4]);
            Oacc[1][4] = MFMA16(pf1, v04, Oacc[1][4]);
            __builtin_amdgcn_s_setprio(0);
        }
        // js = 1: st[2], st[3]
        {
            short8 pf0, pf1;
            #pragma unroll
            for (int half = 0; half < 2; half++)
                #pragma unroll
                for (int r = 0; r < 4; r++) {
                    float p0 = __builtin_amdgcn_exp2f(st[2+half][0][r]);
                    float p1 = __builtin_amdgcn_exp2f(st[2+half][1][r]);
                    lsum4[0][r] += p0;
                    lsum4[1][r] += p1;
                    pf0[half*4+r] = bbits(p0);
                    pf1[half*4+r] = bbits(p1);
                }
            __builtin_amdgcn_s_setprio(1);
            Oacc[0][0] = MFMA16(pf0, v10, Oacc[0][0]);
            Oacc[1][0] = MFMA16(pf1, v10, Oacc[1][0]);
            Oacc[0][1] = MFMA16(pf0, v11, Oacc[0][1]);
            Oacc[1][1] = MFMA16(pf1, v11, Oacc[1][1]);
            Oacc[0][2] = MFMA16(pf0, v12, Oacc[0][2]);
            Oacc[1][2] = MFMA16(pf1, v12, Oacc[1][2]);
            Oacc[0][3] = MFMA16(pf0, v13, Oacc[0][3]);
            Oacc[1][3] = MFMA16(pf1, v13, Oacc[1][3]);
            Oacc[0][4] = MFMA16(pf0, v14, Oacc[0][4]);
            Oacc[1][4] = MFMA16(pf1, v14, Oacc[1][4]);
            __builtin_amdgcn_s_setprio(0);
        }

        // publish next K tile into the OTHER buffer (safe: prev barrier
        // drained all reads of it); single barrier per iteration
        *(uint4*)(nxt + kd0) = kA;
        *(uint4*)(nxt + kd1) = kB;
        *(uint4*)(nxt + kd2) = kC;
        *(uint4*)(nxt + kd3) = kD;
        *(uint4*)(nxt + kd4) = kE;
        *(uint4*)(nxt + kd5) = kF;
        __syncthreads();
    }

    // single l-reduce + normalize + write
    float inv[2];
    #pragma unroll
    for (int nt = 0; nt < 2; nt++) {
        float s = (lsum4[nt][0] + lsum4[nt][1]) + (lsum4[nt][2] + lsum4[nt][3]);
        s += __shfl_xor(s, 16);
        s += __shfl_xor(s, 32);
        inv[nt] = 1.f / s;
    }
    #pragma unroll
    for (int mt = 0; mt < 2; mt++) {
        f32x4 li;
        #pragma unroll
        for (int r = 0; r < 4; r++)
            li[r] = __shfl(inv[mt], (lane & 48) | (lquad*4 + r));
        #pragma unroll
        for (int ne = 0; ne < 5; ne++)
            #pragma unroll
            for (int r = 0; r < 4; r++) {
                int s_row = q0 + wave*32 + mt*16 + lquad*4 + r;
                int e = ne*16 + lcol;
                Cc[(size_t)(b * SEQ + s_row) * D_MODEL + h * D_K + e] =
                    f2b(Oacc[mt][ne][r] * li[r]);
            }
    }
}

// ---------------------------------------------------------------------------
// Kernel 3: output projection out = Cc @ Wo^T + bo via MFMA (unchanged r4).
// ---------------------------------------------------------------------------
__global__ __launch_bounds__(256) void proj_kernel(
    const bf16* __restrict__ Cc, const bf16* __restrict__ Wb,
    const float* __restrict__ bo, float* __restrict__ out)
{
    __shared__ bf16 As[128 * 72];
    __shared__ bf16 Bs[128 * 72];
    const int tid = threadIdx.x;
    const int wave = tid >> 6, lane = tid & 63;
    const int lquad = lane >> 4, lcol = lane & 15;
    const int t0 = blockIdx.x * 128, o0 = blockIdx.y * 128;
    const int mrow = (wave & 1) * 64, ncol = (wave >> 1) * 64;

    // staging maps as individual scalars
    const int i0 = tid, i1 = tid + 256, i2 = tid + 512, i3 = tid + 768;
    const int d0 = (i0>>3)*72 + (i0&7)*8, d1 = (i1>>3)*72 + (i1&7)*8,
              d2 = (i2>>3)*72 + (i2&7)*8, d3 = (i3>>3)*72 + (i3&7)*8;
    const size_t gA0 = (size_t)(t0 + (i0>>3))*D_MODEL + (i0&7)*8;
    const size_t gA1 = (size_t)(t0 + (i1>>3))*D_MODEL + (i1&7)*8;
    const size_t gA2 = (size_t)(t0 + (i2>>3))*D_MODEL + (i2&7)*8;
    const size_t gA3 = (size_t)(t0 + (i3>>3))*D_MODEL + (i3&7)*8;
    const size_t gB0 = (size_t)(o0 + (i0>>3))*D_MODEL + (i0&7)*8;
    const size_t gB1 = (size_t)(o0 + (i1>>3))*D_MODEL + (i1&7)*8;
    const size_t gB2 = (size_t)(o0 + (i2>>3))*D_MODEL + (i2&7)*8;
    const size_t gB3 = (size_t)(o0 + (i3>>3))*D_MODEL + (i3&7)*8;

    // stage K-chunk 0
    *(uint4*)(As + d0) = *(const uint4*)(Cc + gA0);
    *(uint4*)(As + d1) = *(const uint4*)(Cc + gA1);
    *(uint4*)(As + d2) = *(const uint4*)(Cc + gA2);
    *(uint4*)(As + d3) = *(const uint4*)(Cc + gA3);
    *(uint4*)(Bs + d0) = *(const uint4*)(Wb + gB0);
    *(uint4*)(Bs + d1) = *(const uint4*)(Wb + gB1);
    *(uint4*)(Bs + d2) = *(const uint4*)(Wb + gB2);
    *(uint4*)(Bs + d3) = *(const uint4*)(Wb + gB3);
    __syncthreads();

    f32x4 acc[4][4];
    #pragma unroll
    for (int mt = 0; mt < 4; mt++)
        #pragma unroll
        for (int nt = 0; nt < 4; nt++)
            #pragma unroll
            for (int r = 0; r < 4; r++) acc[mt][nt][r] = 0.f;

    for (int kc = 0; kc < 20; kc++) {
        // T14: prefetch next K-chunk into scalar regs (wraps to 0 at end)
        const int kn = (kc < 19) ? (kc + 1) * 64 : 0;
        uint4 pa0 = *(const uint4*)(Cc + gA0 + kn);
        uint4 pa1 = *(const uint4*)(Cc + gA1 + kn);
        uint4 pa2 = *(const uint4*)(Cc + gA2 + kn);
        uint4 pa3 = *(const uint4*)(Cc + gA3 + kn);
        uint4 pb0 = *(const uint4*)(Wb + gB0 + kn);
        uint4 pb1 = *(const uint4*)(Wb + gB1 + kn);
        uint4 pb2 = *(const uint4*)(Wb + gB2 + kn);
        uint4 pb3 = *(const uint4*)(Wb + gB3 + kn);

        __builtin_amdgcn_s_setprio(1);
        #pragma unroll
        for (int ks = 0; ks < 2; ks++) {
            short8 am[4], bn[4];
            #pragma unroll
            for (int t = 0; t < 4; t++) {
                am[t] = *(const short8*)(As + (mrow + t*16 + lcol)*72 + ks*32 + lquad*8);
                bn[t] = *(const short8*)(Bs + (ncol + t*16 + lcol)*72 + ks*32 + lquad*8);
            }
            #pragma unroll
            for (int mt = 0; mt < 4; mt++)
                #pragma unroll
                for (int nt = 0; nt < 4; nt++)
                    acc[mt][nt] = MFMA16(am[mt], bn[nt], acc[mt][nt]);
        }
        __builtin_amdgcn_s_setprio(0);

        // publish: only fast ds_writes between the barriers
        __syncthreads();
        *(uint4*)(As + d0) = pa0;
        *(uint4*)(As + d1) = pa1;
        *(uint4*)(As + d2) = pa2;
        *(uint4*)(As + d3) = pa3;
        *(uint4*)(Bs + d0) = pb0;
        *(uint4*)(Bs + d1) = pb1;
        *(uint4*)(Bs + d2) = pb2;
        *(uint4*)(Bs + d3) = pb3;
        __syncthreads();
    }

    #pragma unroll
    for (int nt = 0; nt < 4; nt++) {
        float bias = bo[o0 + ncol + nt*16 + lcol];
        #pragma unroll
        for (int mt = 0; mt < 4; mt++)
            #pragma unroll
            for (int r = 0; r < 4; r++)
                out[(size_t)(t0 + mrow + mt*16 + lquad*4 + r) * D_MODEL
                    + o0 + ncol + nt*16 + lcol] = acc[mt][nt][r] + bias;
    }
}

// ---------------------------------------------------------------------------
extern "C" void kernel_launch(void* const* d_in, const int* in_sizes, int n_in,
                              void* d_out, int out_size, void* d_ws, size_t ws_size,
                              hipStream_t stream) {
    const float* src = (const float*)d_in[0];
    const float* Wq = (const float*)d_in[3];
    const float* bq = (const float*)d_in[4];
    const float* Wk = (const float*)d_in[5];
    const float* bk = (const float*)d_in[6];
    const float* Wv = (const float*)d_in[7];
    const float* bv = (const float*)d_in[8];
    const float* Wo = (const float*)d_in[9];
    const float* bo = (const float*)d_in[10];
    float* out = (float*)d_out;

    // ws layout (bytes):
    //   Qb bf16 [BH][S][96]    @ 0         12,582,912
    //   Kb bf16 [BH][S][96]    @ 12582912  12,582,912
    //   Vg bf16 [BH][81920]    @ 25165824  10,485,760  (PV-fragment order)
    //   Cc bf16 [B][S][1280]   @ 35651584  10,485,760  (also Wcat before attn)
    //   Wb bf16 [1280][1280]   @ 46137344   3,276,800
    char* ws = (char*)d_ws;
    bf16* Qb = (bf16*)(ws);
    bf16* Kb = (bf16*)(ws + (size_t)12582912);
    bf16* Vg = (bf16*)(ws + (size_t)25165824);
    bf16* Cc = (bf16*)(ws + (size_t)35651584);
    bf16* Wcat = (bf16*)(ws + (size_t)35651584);
    bf16* Wb = (bf16*)(ws + (size_t)46137344);

    cvt_all_kernel<<<dim3(3040), 256, 0, stream>>>(Wq, Wk, Wv, Wcat, Wo, Wb);
    qkv_kernel<<<dim3(BATCH * SEQ / 128, NUM_HEADS), 256, 0, stream>>>(
        src, bq, bk, bv, Wcat, Qb, Kb, Vg);
    attn_kernel<<<dim3(BH, SEQ / 64), 128, 0, stream>>>(Qb, Kb, Vg, Cc);
    proj_kernel<<<dim3(SEQ * BATCH / 128, D_MODEL / 128), 256, 0, stream>>>(
        Cc, Wb, bo, out);
}

// Round 9
// 186.213 us; speedup vs baseline: 1.0076x; 1.0076x over previous
//
#include <hip/hip_runtime.h>
#include <hip/hip_bf16.h>

#define D_MODEL 1280
#define NUM_HEADS 16
#define D_K 80
#define DP 96            // head dim padded to 3*32 for MFMA K-steps
#define SEQ 1024
#define BATCH 4
#define BH (BATCH*NUM_HEADS)

typedef __hip_bfloat16 bf16;
typedef short short8 __attribute__((ext_vector_type(8)));
typedef short short4v __attribute__((ext_vector_type(4)));
typedef float f32x4 __attribute__((ext_vector_type(4)));

__device__ __forceinline__ float b2f(bf16 x) { return __bfloat162float(x); }
__device__ __forceinline__ bf16 f2b(float x) { return __float2bfloat16(x); }
__device__ __forceinline__ short bbits(float x) {
    union { bf16 b; short s; } u; u.b = __float2bfloat16(x); return u.s;
}

#define MFMA16(a, b, c) __builtin_amdgcn_mfma_f32_16x16x32_bf16(a, b, c, 0, 0, 0)

// ---------------------------------------------------------------------------
// Kernel 0 (merged): pack Wq|Wk|Wv -> Wcat[h][240][96] bf16 with the
// channel-shuffle permutation folded into the K(input)-dim. Also Wo -> bf16.
// ---------------------------------------------------------------------------
__global__ __launch_bounds__(256) void cvt_all_kernel(
    const float* __restrict__ Wq, const float* __restrict__ Wk,
    const float* __restrict__ Wv, bf16* __restrict__ Wcat,
    const float* __restrict__ Wo, bf16* __restrict__ Wb)
{
    if (blockIdx.x < 1440) {
        int idx = blockIdx.x * 256 + threadIdx.x;
        int col = idx % 96;
        int row = (idx / 96) % 240;
        int h   = idx / (96 * 240);
        int mat = row / 80, e = row % 80;
        int c = col >> 4, j = col & 15;          // e' = c*16 + j
        const float* W = (mat == 0) ? Wq : (mat == 1) ? Wk : Wv;
        float v = (col < 80) ? W[(size_t)(h * 80 + e) * 80 + (j * 5 + c)] : 0.f;
        Wcat[idx] = f2b(v);
    } else {
        int idx = ((blockIdx.x - 1440) * 256 + threadIdx.x) * 4;
        float4 v = *(const float4*)(Wo + idx);
        Wb[idx]     = f2b(v.x);
        Wb[idx + 1] = f2b(v.y);
        Wb[idx + 2] = f2b(v.z);
        Wb[idx + 3] = f2b(v.w);
    }
}

// ---------------------------------------------------------------------------
// Kernel 1: per-head QKV projection via MFMA, register-direct X fragments.
// V is stored in PV-FRAGMENT order (unchanged from round 8).
// ---------------------------------------------------------------------------
__global__ __launch_bounds__(256) void qkv_kernel(
    const float* __restrict__ src,
    const float* __restrict__ bq, const float* __restrict__ bk,
    const float* __restrict__ bv, const bf16* __restrict__ Wcat,
    bf16* __restrict__ Qb, bf16* __restrict__ Kb, bf16* __restrict__ Vg)
{
    const int h = blockIdx.y;
    const int b = blockIdx.x >> 3;
    const int s0 = (blockIdx.x & 7) * 128;
    const int tid = threadIdx.x;
    const int wave = tid >> 6, lane = tid & 63;
    const int lquad = lane >> 4, lcol = lane & 15;
    const int bh = b * NUM_HEADS + h;

    // X fragments straight from global (permuted-K ordering)
    short8 xf[2][3];
    #pragma unroll
    for (int mt = 0; mt < 2; mt++)
        #pragma unroll
        for (int ks = 0; ks < 3; ks++) {
            const int c  = 2 * ks + (lquad >> 1);
            const int j0 = (lquad & 1) * 8;
            short8 t = {0, 0, 0, 0, 0, 0, 0, 0};
            if (c < 5) {   // c==5 is the zero pad (W pad cols are zero too)
                const float* p = src
                    + (size_t)(b * SEQ + s0 + wave * 32 + mt * 16 + lcol) * D_MODEL
                    + c * 256 + h * 16 + j0;
                float4 v0 = *(const float4*)p;
                float4 v1 = *(const float4*)(p + 4);
                t[0] = bbits(v0.x); t[1] = bbits(v0.y);
                t[2] = bbits(v0.z); t[3] = bbits(v0.w);
                t[4] = bbits(v1.x); t[5] = bbits(v1.y);
                t[6] = bbits(v1.z); t[7] = bbits(v1.w);
            }
            xf[mt][ks] = t;
        }

    const bf16* Wh = Wcat + (size_t)h * 240 * 96;
    const float qscale = 1.4426950408889634f * 0.11180339887498949f;
    const f32x4 fzero = {0.f, 0.f, 0.f, 0.f};

    // ---- Q and K: D[token][e] ----
    #pragma unroll
    for (int mat = 0; mat < 2; mat++) {
        const bf16* Wm = Wh + mat * 80 * 96;
        short8 wf[5][3];
        #pragma unroll
        for (int n = 0; n < 5; n++)
            #pragma unroll
            for (int ks = 0; ks < 3; ks++)
                wf[n][ks] = *(const short8*)(Wm + (n*16 + lcol)*96 + ks*32 + lquad*8);

        f32x4 acc[2][5];
        #pragma unroll
        for (int n = 0; n < 5; n++) {          // first ks folds zero-init
            acc[0][n] = MFMA16(xf[0][0], wf[n][0], fzero);
            acc[1][n] = MFMA16(xf[1][0], wf[n][0], fzero);
        }
        #pragma unroll
        for (int ks = 1; ks < 3; ks++)
            #pragma unroll
            for (int n = 0; n < 5; n++) {
                acc[0][n] = MFMA16(xf[0][ks], wf[n][ks], acc[0][n]);
                acc[1][n] = MFMA16(xf[1][ks], wf[n][ks], acc[1][n]);
            }

        const float* bias = (mat == 0) ? bq : bk;
        bf16* Out = (mat == 0) ? Qb : Kb;
        const float scale = (mat == 0) ? qscale : 1.f;
        #pragma unroll
        for (int n = 0; n < 5; n++) {
            float bb = bias[h * 80 + n * 16 + lcol];
            #pragma unroll
            for (int mt = 0; mt < 2; mt++)
                #pragma unroll
                for (int r = 0; r < 4; r++) {
                    int srow = s0 + wave*32 + mt*16 + lquad*4 + r;
                    Out[((size_t)bh * SEQ + srow) * DP + n*16 + lcol] =
                        f2b((acc[mt][n][r] + bb) * scale);
                }
        }
    }
    // zero pad e = 80..95 for Q and K (128 rows, 256 threads)
    {
        int i = tid >> 1, half = tid & 1;
        size_t row = ((size_t)bh * SEQ + s0 + i) * DP + 80 + half * 8;
        *(uint4*)(Qb + row) = make_uint4(0, 0, 0, 0);
        *(uint4*)(Kb + row) = make_uint4(0, 0, 0, 0);
    }

    // ---- V: PV-fragment-order store ----
    {
        const bf16* Wm = Wh + 2 * 80 * 96;
        short8 wf[5][3];
        #pragma unroll
        for (int m = 0; m < 5; m++)
            #pragma unroll
            for (int ks = 0; ks < 3; ks++)
                wf[m][ks] = *(const short8*)(Wm + (m*16 + lcol)*96 + ks*32 + lquad*8);

        f32x4 acc[5][2];
        #pragma unroll
        for (int m = 0; m < 5; m++) {          // first ks folds zero-init
            acc[m][0] = MFMA16(wf[m][0], xf[0][0], fzero);
            acc[m][1] = MFMA16(wf[m][0], xf[1][0], fzero);
        }
        #pragma unroll
        for (int ks = 1; ks < 3; ks++)
            #pragma unroll
            for (int m = 0; m < 5; m++) {
                acc[m][0] = MFMA16(wf[m][ks], xf[0][ks], acc[m][0]);
                acc[m][1] = MFMA16(wf[m][ks], xf[1][ks], acc[m][1]);
            }

        #pragma unroll
        for (int m = 0; m < 5; m++) {
            float4 bb4 = *(const float4*)(bv + h * 80 + m * 16 + lquad * 4);
            float bb[4] = {bb4.x, bb4.y, bb4.z, bb4.w};
            #pragma unroll
            for (int nt = 0; nt < 2; nt++)
                #pragma unroll
                for (int r = 0; r < 4; r++) {
                    int elow  = lquad * 4 + r;           // e & 15
                    int token = s0 + wave * 32 + nt * 16 + lcol;
                    int kt  = token >> 6;
                    int js  = (token >> 5) & 1;
                    int jj  = ((token >> 4) & 1) * 4 + (token & 3);
                    int lqs = (token >> 2) & 3;
                    size_t el = (size_t)bh * 81920
                              + (size_t)((kt * 2 + js) * 5 + m) * 512
                              + elow * 32 + lqs * 8 + jj;
                    Vg[el] = f2b(acc[m][nt][r] + bb[r]);
                }
        }
    }
}

// ---------------------------------------------------------------------------
// Kernel 2: MFMA flash attention (unchanged from round 8).
// P lane-local, V coalesced from L2 in PV-fragment order, K double-buffered
// in LDS with one barrier/iter. LDS 26,624 B = Ks0|Ks1.
// ---------------------------------------------------------------------------
__global__ __launch_bounds__(128, 2) void attn_kernel(
    const bf16* __restrict__ Qb, const bf16* __restrict__ Kb,
    const bf16* __restrict__ Vg, bf16* __restrict__ Cc)
{
    __shared__ char smem[26624];
    bf16* Ks0 = (bf16*)smem;
    bf16* Ks1 = (bf16*)(smem + 13312);

    const int tid = threadIdx.x;
    const int wave = tid >> 6, lane = tid & 63;
    const int lquad = lane >> 4, lcol = lane & 15;
    const int bh = blockIdx.x;
    const int b = bh >> 4, h = bh & 15;
    const int q0 = blockIdx.y * 64;

    const uint4* Kg = (const uint4*)(Kb + (size_t)bh * SEQ * DP);
    // V: per-lane offset inside each coalesced 512-element fragment block
    const bf16* Vb = Vg + (size_t)bh * 81920 + lcol * 32 + lquad * 8;

    // K staging map as individual scalars (NO arrays -> no scratch demotion)
    const int i0 = tid, i1 = tid + 128, i2 = tid + 256,
              i3 = tid + 384, i4 = tid + 512, i5 = tid + 640;
    const int kd0 = (i0/12)*104 + (i0%12)*8, kd1 = (i1/12)*104 + (i1%12)*8,
              kd2 = (i2/12)*104 + (i2%12)*8, kd3 = (i3/12)*104 + (i3%12)*8,
              kd4 = (i4/12)*104 + (i4%12)*8, kd5 = (i5/12)*104 + (i5%12)*8;

    // Q fragments direct from global (read once per block)
    short8 qf[2][3];
    #pragma unroll
    for (int nt = 0; nt < 2; nt++)
        #pragma unroll
        for (int ks = 0; ks < 3; ks++)
            qf[nt][ks] = *(const short8*)(
                Qb + ((size_t)bh * SEQ + q0 + wave*32 + nt*16 + lcol) * DP
                   + ks*32 + lquad*8);

    // stage K tile 0 into Ks0
    *(uint4*)(Ks0 + kd0) = Kg[i0];
    *(uint4*)(Ks0 + kd1) = Kg[i1];
    *(uint4*)(Ks0 + kd2) = Kg[i2];
    *(uint4*)(Ks0 + kd3) = Kg[i3];
    *(uint4*)(Ks0 + kd4) = Kg[i4];
    *(uint4*)(Ks0 + kd5) = Kg[i5];
    __syncthreads();

    f32x4 Oacc[2][5];
    #pragma unroll
    for (int mt = 0; mt < 2; mt++)
        #pragma unroll
        for (int ne = 0; ne < 5; ne++)
            #pragma unroll
            for (int r = 0; r < 4; r++) Oacc[mt][ne][r] = 0.f;

    f32x4 lsum4[2];
    #pragma unroll
    for (int nt = 0; nt < 2; nt++)
        #pragma unroll
        for (int r = 0; r < 4; r++) lsum4[nt][r] = 0.f;

    const f32x4 fzero = {0.f, 0.f, 0.f, 0.f};

    for (int kt = 0; kt < 16; kt++) {
        const bf16* cur = (kt & 1) ? Ks1 : Ks0;
        bf16*       nxt = (kt & 1) ? Ks0 : Ks1;

        // V fragments for THIS tile: coalesced 1KB/wave loads, issued early
        const bf16* Vk = Vb + (size_t)kt * 5120;
        short8 v00 = *(const short8*)(Vk);              // js=0, ne=0
        short8 v01 = *(const short8*)(Vk + 512);
        short8 v02 = *(const short8*)(Vk + 1024);
        short8 v03 = *(const short8*)(Vk + 1536);
        short8 v04 = *(const short8*)(Vk + 2048);
        short8 v10 = *(const short8*)(Vk + 2560);       // js=1, ne=0
        short8 v11 = *(const short8*)(Vk + 3072);
        short8 v12 = *(const short8*)(Vk + 3584);
        short8 v13 = *(const short8*)(Vk + 4096);
        short8 v14 = *(const short8*)(Vk + 4608);

        // T14: next K tile into scalar regs; straight-line (wraps at end)
        const int ktn = (kt + 1) & 15;
        uint4 kA = Kg[ktn * 768 + i0];
        uint4 kB = Kg[ktn * 768 + i1];
        uint4 kC = Kg[ktn * 768 + i2];
        uint4 kD = Kg[ktn * 768 + i3];
        uint4 kE = Kg[ktn * 768 + i4];
        uint4 kF = Kg[ktn * 768 + i5];

        // S^T = K·Q^T (first ks folds the zero-init)
        f32x4 st[4][2];
        __builtin_amdgcn_s_setprio(1);
        #pragma unroll
        for (int mt = 0; mt < 4; mt++) {
            short8 af = *(const short8*)(cur + (mt*16 + lcol)*104 + lquad*8);
            st[mt][0] = MFMA16(af, qf[0][0], fzero);
            st[mt][1] = MFMA16(af, qf[1][0], fzero);
        }
        #pragma unroll
        for (int ks = 1; ks < 3; ks++)
            #pragma unroll
            for (int mt = 0; mt < 4; mt++) {
                short8 af = *(const short8*)(cur + (mt*16 + lcol)*104 + ks*32 + lquad*8);
                st[mt][0] = MFMA16(af, qf[0][ks], st[mt][0]);
                st[mt][1] = MFMA16(af, qf[1][ks], st[mt][1]);
            }
        __builtin_amdgcn_s_setprio(0);

        // softmax + PV, fused per js; P fragments lane-local
        // js = 0: st[0], st[1]
        {
            short8 pf0, pf1;
            #pragma unroll
            for (int half = 0; half < 2; half++)
                #pragma unroll
                for (int r = 0; r < 4; r++) {
                    float p0 = __builtin_amdgcn_exp2f(st[half][0][r]);
                    float p1 = __builtin_amdgcn_exp2f(st[half][1][r]);
                    lsum4[0][r] += p0;
                    lsum4[1][r] += p1;
                    pf0[half*4+r] = bbits(p0);
                    pf1[half*4+r] = bbits(p1);
                }
            __builtin_amdgcn_s_setprio(1);
            Oacc[0][0] = MFMA16(pf0, v00, Oacc[0][0]);
            Oacc[1][0] = MFMA16(pf1, v00, Oacc[1][0]);
            Oacc[0][1] = MFMA16(pf0, v01, Oacc[0][1]);
            Oacc[1][1] = MFMA16(pf1, v01, Oacc[1][1]);
            Oacc[0][2] = MFMA16(pf0, v02, Oacc[0][2]);
            Oacc[1][2] = MFMA16(pf1, v02, Oacc[1][2]);
            Oacc[0][3] = MFMA16(pf0, v03, Oacc[0][3]);
            Oacc[1][3] = MFMA16(pf1, v03, Oacc[1][3]);
            Oacc[0][4] = MFMA16(pf0, v04, Oacc[0][4]);
            Oacc[1][4] = MFMA16(pf1, v04, Oacc[1][4]);
            __builtin_amdgcn_s_setprio(0);
        }
        // js = 1: st[2], st[3]
        {
            short8 pf0, pf1;
            #pragma unroll
            for (int half = 0; half < 2; half++)
                #pragma unroll
                for (int r = 0; r < 4; r++) {
                    float p0 = __builtin_amdgcn_exp2f(st[2+half][0][r]);
                    float p1 = __builtin_amdgcn_exp2f(st[2+half][1][r]);
                    lsum4[0][r] += p0;
                    lsum4[1][r] += p1;
                    pf0[half*4+r] = bbits(p0);
                    pf1[half*4+r] = bbits(p1);
                }
            __builtin_amdgcn_s_setprio(1);
            Oacc[0][0] = MFMA16(pf0, v10, Oacc[0][0]);
            Oacc[1][0] = MFMA16(pf1, v10, Oacc[1][0]);
            Oacc[0][1] = MFMA16(pf0, v11, Oacc[0][1]);
            Oacc[1][1] = MFMA16(pf1, v11, Oacc[1][1]);
            Oacc[0][2] = MFMA16(pf0, v12, Oacc[0][2]);
            Oacc[1][2] = MFMA16(pf1, v12, Oacc[1][2]);
            Oacc[0][3] = MFMA16(pf0, v13, Oacc[0][3]);
            Oacc[1][3] = MFMA16(pf1, v13, Oacc[1][3]);
            Oacc[0][4] = MFMA16(pf0, v14, Oacc[0][4]);
            Oacc[1][4] = MFMA16(pf1, v14, Oacc[1][4]);
            __builtin_amdgcn_s_setprio(0);
        }

        // publish next K tile into the OTHER buffer; single barrier per iter
        *(uint4*)(nxt + kd0) = kA;
        *(uint4*)(nxt + kd1) = kB;
        *(uint4*)(nxt + kd2) = kC;
        *(uint4*)(nxt + kd3) = kD;
        *(uint4*)(nxt + kd4) = kE;
        *(uint4*)(nxt + kd5) = kF;
        __syncthreads();
    }

    // single l-reduce + normalize + write
    float inv[2];
    #pragma unroll
    for (int nt = 0; nt < 2; nt++) {
        float s = (lsum4[nt][0] + lsum4[nt][1]) + (lsum4[nt][2] + lsum4[nt][3]);
        s += __shfl_xor(s, 16);
        s += __shfl_xor(s, 32);
        inv[nt] = 1.f / s;
    }
    #pragma unroll
    for (int mt = 0; mt < 2; mt++) {
        f32x4 li;
        #pragma unroll
        for (int r = 0; r < 4; r++)
            li[r] = __shfl(inv[mt], (lane & 48) | (lquad*4 + r));
        #pragma unroll
        for (int ne = 0; ne < 5; ne++)
            #pragma unroll
            for (int r = 0; r < 4; r++) {
                int s_row = q0 + wave*32 + mt*16 + lquad*4 + r;
                int e = ne*16 + lcol;
                Cc[(size_t)(b * SEQ + s_row) * D_MODEL + h * D_K + e] =
                    f2b(Oacc[mt][ne][r] * li[r]);
            }
    }
}

// ---------------------------------------------------------------------------
// Kernel 3: output projection out = Cc @ Wo^T + bo via MFMA.
// RETILED 128x128 -> 64x128: grid (64,10)=640 blocks = 2.5 blocks/CU
// (was 320 = 1.25/CU, latency-bound). 256 thr = 4 waves in 2x2; wave owns
// 32x64 output (acc[2][4]). T14 scalar-reg prefetch retained.
// LDS 27,648 B: As 64x72 | Bs 128x72.
// ---------------------------------------------------------------------------
__global__ __launch_bounds__(256) void proj_kernel(
    const bf16* __restrict__ Cc, const bf16* __restrict__ Wb,
    const float* __restrict__ bo, float* __restrict__ out)
{
    __shared__ bf16 As[64 * 72];
    __shared__ bf16 Bs[128 * 72];
    const int tid = threadIdx.x;
    const int wave = tid >> 6, lane = tid & 63;
    const int lquad = lane >> 4, lcol = lane & 15;
    const int t0 = blockIdx.x * 64, o0 = blockIdx.y * 128;
    const int mrow = (wave >> 1) * 32, ncol = (wave & 1) * 64;

    // staging maps as individual scalars
    // A: 64 rows x 8 uint4 = 512 -> 2/thread; B: 128 rows x 8 = 1024 -> 4/thread
    const int a0 = tid, a1 = tid + 256;
    const int b0 = tid, b1 = tid + 256, b2 = tid + 512, b3 = tid + 768;
    const int dA0 = (a0>>3)*72 + (a0&7)*8, dA1 = (a1>>3)*72 + (a1&7)*8;
    const int dB0 = (b0>>3)*72 + (b0&7)*8, dB1 = (b1>>3)*72 + (b1&7)*8,
              dB2 = (b2>>3)*72 + (b2&7)*8, dB3 = (b3>>3)*72 + (b3&7)*8;
    const size_t gA0 = (size_t)(t0 + (a0>>3))*D_MODEL + (a0&7)*8;
    const size_t gA1 = (size_t)(t0 + (a1>>3))*D_MODEL + (a1&7)*8;
    const size_t gB0 = (size_t)(o0 + (b0>>3))*D_MODEL + (b0&7)*8;
    const size_t gB1 = (size_t)(o0 + (b1>>3))*D_MODEL + (b1&7)*8;
    const size_t gB2 = (size_t)(o0 + (b2>>3))*D_MODEL + (b2&7)*8;
    const size_t gB3 = (size_t)(o0 + (b3>>3))*D_MODEL + (b3&7)*8;

    // stage K-chunk 0
    *(uint4*)(As + dA0) = *(const uint4*)(Cc + gA0);
    *(uint4*)(As + dA1) = *(const uint4*)(Cc + gA1);
    *(uint4*)(Bs + dB0) = *(const uint4*)(Wb + gB0);
    *(uint4*)(Bs + dB1) = *(const uint4*)(Wb + gB1);
    *(uint4*)(Bs + dB2) = *(const uint4*)(Wb + gB2);
    *(uint4*)(Bs + dB3) = *(const uint4*)(Wb + gB3);
    __syncthreads();

    f32x4 acc[2][4];
    #pragma unroll
    for (int mt = 0; mt < 2; mt++)
        #pragma unroll
        for (int nt = 0; nt < 4; nt++)
            #pragma unroll
            for (int r = 0; r < 4; r++) acc[mt][nt][r] = 0.f;

    for (int kc = 0; kc < 20; kc++) {
        // T14: prefetch next K-chunk into scalar regs (wraps to 0 at end)
        const int kn = (kc < 19) ? (kc + 1) * 64 : 0;
        uint4 pa0 = *(const uint4*)(Cc + gA0 + kn);
        uint4 pa1 = *(const uint4*)(Cc + gA1 + kn);
        uint4 pb0 = *(const uint4*)(Wb + gB0 + kn);
        uint4 pb1 = *(const uint4*)(Wb + gB1 + kn);
        uint4 pb2 = *(const uint4*)(Wb + gB2 + kn);
        uint4 pb3 = *(const uint4*)(Wb + gB3 + kn);

        __builtin_amdgcn_s_setprio(1);
        #pragma unroll
        for (int ks = 0; ks < 2; ks++) {
            short8 am[2], bn[4];
            #pragma unroll
            for (int t = 0; t < 2; t++)
                am[t] = *(const short8*)(As + (mrow + t*16 + lcol)*72 + ks*32 + lquad*8);
            #pragma unroll
            for (int t = 0; t < 4; t++)
                bn[t] = *(const short8*)(Bs + (ncol + t*16 + lcol)*72 + ks*32 + lquad*8);
            #pragma unroll
            for (int mt = 0; mt < 2; mt++)
                #pragma unroll
                for (int nt = 0; nt < 4; nt++)
                    acc[mt][nt] = MFMA16(am[mt], bn[nt], acc[mt][nt]);
        }
        __builtin_amdgcn_s_setprio(0);

        // publish: only fast ds_writes between the barriers
        __syncthreads();
        *(uint4*)(As + dA0) = pa0;
        *(uint4*)(As + dA1) = pa1;
        *(uint4*)(Bs + dB0) = pb0;
        *(uint4*)(Bs + dB1) = pb1;
        *(uint4*)(Bs + dB2) = pb2;
        *(uint4*)(Bs + dB3) = pb3;
        __syncthreads();
    }

    #pragma unroll
    for (int nt = 0; nt < 4; nt++) {
        float bias = bo[o0 + ncol + nt*16 + lcol];
        #pragma unroll
        for (int mt = 0; mt < 2; mt++)
            #pragma unroll
            for (int r = 0; r < 4; r++)
                out[(size_t)(t0 + mrow + mt*16 + lquad*4 + r) * D_MODEL
                    + o0 + ncol + nt*16 + lcol] = acc[mt][nt][r] + bias;
    }
}

// ---------------------------------------------------------------------------
extern "C" void kernel_launch(void* const* d_in, const int* in_sizes, int n_in,
                              void* d_out, int out_size, void* d_ws, size_t ws_size,
                              hipStream_t stream) {
    const float* src = (const float*)d_in[0];
    const float* Wq = (const float*)d_in[3];
    const float* bq = (const float*)d_in[4];
    const float* Wk = (const float*)d_in[5];
    const float* bk = (const float*)d_in[6];
    const float* Wv = (const float*)d_in[7];
    const float* bv = (const float*)d_in[8];
    const float* Wo = (const float*)d_in[9];
    const float* bo = (const float*)d_in[10];
    float* out = (float*)d_out;

    // ws layout (bytes):
    //   Qb bf16 [BH][S][96]    @ 0         12,582,912
    //   Kb bf16 [BH][S][96]    @ 12582912  12,582,912
    //   Vg bf16 [BH][81920]    @ 25165824  10,485,760  (PV-fragment order)
    //   Cc bf16 [B][S][1280]   @ 35651584  10,485,760  (also Wcat before attn)
    //   Wb bf16 [1280][1280]   @ 46137344   3,276,800
    char* ws = (char*)d_ws;
    bf16* Qb = (bf16*)(ws);
    bf16* Kb = (bf16*)(ws + (size_t)12582912);
    bf16* Vg = (bf16*)(ws + (size_t)25165824);
    bf16* Cc = (bf16*)(ws + (size_t)35651584);
    bf16* Wcat = (bf16*)(ws + (size_t)35651584);
    bf16* Wb = (bf16*)(ws + (size_t)46137344);

    cvt_all_kernel<<<dim3(3040), 256, 0, stream>>>(Wq, Wk, Wv, Wcat, Wo, Wb);
    qkv_kernel<<<dim3(BATCH * SEQ / 128, NUM_HEADS), 256, 0, stream>>>(
        src, bq, bk, bv, Wcat, Qb, Kb, Vg);
    attn_kernel<<<dim3(BH, SEQ / 64), 128, 0, stream>>>(Qb, Kb, Vg, Cc);
    proj_kernel<<<dim3(SEQ * BATCH / 64, D_MODEL / 128), 256, 0, stream>>>(
        Cc, Wb, bo, out);
}